// Round 1
// baseline (1253.331 us; speedup 1.0000x reference)
//
#include <hip/hip_runtime.h>
#include <hip/hip_bf16.h>

#define EMB 768
#define DH 96
#define NHEAD 8
#define NBATCH 32
#define SEQ 512
#define MROWS (NBATCH * SEQ)   // 16384

// ---------------- Projection: xp[h][m][d] = sum_e x[m][e] * w[h][e][d] ----------------
// Tiled f32 GEMM: M-tile 64, N = 96 (full head dim), K-tile 64.
__global__ __launch_bounds__(256, 2) void proj_kernel(
    const float* __restrict__ kin, const float* __restrict__ qin,
    const float* __restrict__ wk, const float* __restrict__ wq,
    float* __restrict__ kx, float* __restrict__ qx)
{
    const int rt = blockIdx.x;       // row tile (64 rows)
    const int h  = blockIdx.y;       // head
    const int zz = blockIdx.z;       // 0 = k, 1 = q
    const float* x = zz ? qin : kin;
    const float* w = (zz ? wq : wk) + (size_t)h * EMB * DH;
    float* xp = (zz ? qx : kx) + (size_t)h * MROWS * DH;

    __shared__ float xs[64][68];     // transposed x tile: xs[e][row], pad to 68 for b128 align
    __shared__ float wsh[64][96];    // w tile: wsh[e][d]

    const int t  = threadIdx.x;
    const int ty = t >> 4;           // 0..15 -> 4 rows each
    const int tx = t & 15;           // 0..15 -> 6 cols each
    const int r0 = rt * 64;

    float acc[4][6];
    #pragma unroll
    for (int i = 0; i < 4; ++i)
        #pragma unroll
        for (int j = 0; j < 6; ++j) acc[i][j] = 0.f;

    for (int kt = 0; kt < EMB / 64; ++kt) {
        const int e0 = kt * 64;
        __syncthreads();
        // load x tile (64 rows x 64 cols), store transposed
        #pragma unroll
        for (int i = 0; i < 4; ++i) {
            const int f = i * 256 + t;
            const int row = f >> 4, c4 = f & 15;
            float4 g = *(const float4*)&x[(size_t)(r0 + row) * EMB + e0 + c4 * 4];
            xs[c4 * 4 + 0][row] = g.x;
            xs[c4 * 4 + 1][row] = g.y;
            xs[c4 * 4 + 2][row] = g.z;
            xs[c4 * 4 + 3][row] = g.w;
        }
        // load w tile (64 x 96)
        #pragma unroll
        for (int i = 0; i < 6; ++i) {
            const int f = i * 256 + t;
            const int er = f / 24, c4 = f % 24;
            *(float4*)&wsh[er][c4 * 4] = *(const float4*)&w[(size_t)(e0 + er) * DH + c4 * 4];
        }
        __syncthreads();
        #pragma unroll
        for (int kk = 0; kk < 64; ++kk) {
            float4 a = *(const float4*)&xs[kk][ty * 4];
            float b[6];
            #pragma unroll
            for (int j = 0; j < 6; ++j) b[j] = wsh[kk][tx * 6 + j];
            const float av[4] = {a.x, a.y, a.z, a.w};
            #pragma unroll
            for (int i = 0; i < 4; ++i)
                #pragma unroll
                for (int j = 0; j < 6; ++j)
                    acc[i][j] = fmaf(av[i], b[j], acc[i][j]);
        }
    }
    // epilogue
    #pragma unroll
    for (int i = 0; i < 4; ++i) {
        float* op = &xp[(size_t)(r0 + ty * 4 + i) * DH + tx * 6];
        #pragma unroll
        for (int j = 0; j < 6; ++j) op[j] = acc[i][j];
    }
}

// ---------------- Attention: per (h,b), thread = one q row ----------------
// score = qx . kx / sqrt(96); fixed-shift softmax (exact): p = exp(s*scale - 12)
__global__ __launch_bounds__(256, 2) void attn_kernel(
    const float* __restrict__ kx, const float* __restrict__ qx,
    float* __restrict__ out)
{
    const int qh = blockIdx.x;   // q half: 0/1
    const int b  = blockIdx.y;
    const int h  = blockIdx.z;
    const int t  = threadIdx.x;
    const int qrow = qh * 256 + t;
    const size_t hb = ((size_t)h * NBATCH + b) * SEQ * DH;

    __shared__ float kb[128 * DH];   // 48 KB chunk of kx

    float4 q4[24], a4[24];
    const float4* qptr = (const float4*)(qx + hb + (size_t)qrow * DH);
    #pragma unroll
    for (int i = 0; i < 24; ++i) {
        q4[i] = qptr[i];
        a4[i] = make_float4(0.f, 0.f, 0.f, 0.f);
    }
    float l = 0.f;
    const float scale = 0.10206207261596575f;  // 1/sqrt(96)

    for (int kc = 0; kc < 4; ++kc) {
        __syncthreads();
        const float4* src = (const float4*)(kx + hb + (size_t)kc * 128 * DH);
        float4* dst = (float4*)kb;
        #pragma unroll
        for (int i = 0; i < 12; ++i) dst[i * 256 + t] = src[i * 256 + t];
        __syncthreads();

        for (int kk = 0; kk < 128; ++kk) {
            const float4* krow = (const float4*)(kb + kk * DH);
            float s0 = 0.f, s1 = 0.f, s2 = 0.f, s3 = 0.f;
            #pragma unroll
            for (int i = 0; i < 24; ++i) {
                float4 kv = krow[i];
                s0 = fmaf(q4[i].x, kv.x, s0);
                s1 = fmaf(q4[i].y, kv.y, s1);
                s2 = fmaf(q4[i].z, kv.z, s2);
                s3 = fmaf(q4[i].w, kv.w, s3);
            }
            float s = (s0 + s1) + (s2 + s3);
            float p = __expf(fmaf(s, scale, -12.0f));
            l += p;
            // prevent CSE from keeping 24 float4 of krow live across both loops
            asm volatile("" ::: "memory");
            #pragma unroll
            for (int i = 0; i < 24; ++i) {
                float4 kv = krow[i];
                a4[i].x = fmaf(p, kv.x, a4[i].x);
                a4[i].y = fmaf(p, kv.y, a4[i].y);
                a4[i].z = fmaf(p, kv.z, a4[i].z);
                a4[i].w = fmaf(p, kv.w, a4[i].w);
            }
        }
    }

    const float inv = 1.0f / l;
    float4* op = (float4*)(out + ((size_t)b * SEQ + qrow) * (NHEAD * DH) + h * DH);
    #pragma unroll
    for (int i = 0; i < 24; ++i) {
        float4 v = a4[i];
        op[i] = make_float4(v.x * inv, v.y * inv, v.z * inv, v.w * inv);
    }
}

extern "C" void kernel_launch(void* const* d_in, const int* in_sizes, int n_in,
                              void* d_out, int out_size, void* d_ws, size_t ws_size,
                              hipStream_t stream) {
    const float* k    = (const float*)d_in[0];
    const float* q    = (const float*)d_in[1];
    const float* w_kx = (const float*)d_in[2];
    const float* w_qx = (const float*)d_in[3];
    float* out = (float*)d_out;

    float* kx = (float*)d_ws;                                   // [H, M, D] = 50.3 MB
    float* qx = kx + (size_t)NHEAD * MROWS * DH;                // another 50.3 MB

    dim3 pgrid(MROWS / 64, NHEAD, 2);
    proj_kernel<<<pgrid, 256, 0, stream>>>(k, q, w_kx, w_qx, kx, qx);

    dim3 agrid(SEQ / 256, NBATCH, NHEAD);
    attn_kernel<<<agrid, 256, 0, stream>>>(kx, qx, out);
}

// Round 2
// 145.587 us; speedup vs baseline: 8.6088x; 8.6088x over previous
//
#include <hip/hip_runtime.h>
#include <hip/hip_bf16.h>

typedef short short8 __attribute__((ext_vector_type(8)));
typedef float floatx4 __attribute__((ext_vector_type(4)));

#define EMB 768
#define DH 96
#define NHEAD 8
#define NBATCH 32
#define SEQ 512
#define MROWS (NBATCH * SEQ)   // 16384

__device__ __forceinline__ unsigned short f2bf(float x) {
    unsigned int u = __float_as_uint(x);
    unsigned int r = (u + 0x7fffu + ((u >> 16) & 1u)) >> 16;   // RNE
    return (unsigned short)r;
}

// ---------- convert k/q f32 -> bf16 ----------
__global__ __launch_bounds__(256) void cvt_x_kernel(
    const float* __restrict__ kin, const float* __restrict__ qin,
    unsigned short* __restrict__ kb, unsigned short* __restrict__ qb)
{
    const float* src = blockIdx.y ? qin : kin;
    unsigned short* dst = blockIdx.y ? qb : kb;
    const size_t i = ((size_t)blockIdx.x * 256 + threadIdx.x) * 8;
    float4 a = *(const float4*)(src + i);
    float4 b = *(const float4*)(src + i + 4);
    short8 o;
    o[0] = (short)f2bf(a.x); o[1] = (short)f2bf(a.y);
    o[2] = (short)f2bf(a.z); o[3] = (short)f2bf(a.w);
    o[4] = (short)f2bf(b.x); o[5] = (short)f2bf(b.y);
    o[6] = (short)f2bf(b.z); o[7] = (short)f2bf(b.w);
    *(short8*)(dst + i) = o;
}

// ---------- transpose+convert weights: wt[h*96+d][e] = w[h][e][d] ----------
__global__ __launch_bounds__(256) void cvt_w_kernel(
    const float* __restrict__ wk, const float* __restrict__ wq,
    unsigned short* __restrict__ wtk, unsigned short* __restrict__ wtq)
{
    __shared__ float ws[64][97];
    const int h = blockIdx.x, et = blockIdx.y;
    const float* wsrc = (blockIdx.z ? wq : wk) + (size_t)h * EMB * DH;
    unsigned short* o = blockIdx.z ? wtq : wtk;
    const int t = threadIdx.x;
    const int e0 = et * 64;
    #pragma unroll
    for (int i = 0; i < 6; ++i) {
        int f = i * 256 + t;              // 1536 tasks: 64 e-rows x 24 float4
        int e = f / 24, c = f % 24;
        float4 v = *(const float4*)(wsrc + (size_t)(e0 + e) * DH + c * 4);
        ws[e][c*4+0] = v.x; ws[e][c*4+1] = v.y; ws[e][c*4+2] = v.z; ws[e][c*4+3] = v.w;
    }
    __syncthreads();
    #pragma unroll
    for (int i = 0; i < 3; ++i) {
        int f = i * 256 + t;              // 768 tasks: 96 d x 8 chunks
        int d = f >> 3, c8 = f & 7;
        short8 v;
        #pragma unroll
        for (int j = 0; j < 8; ++j) v[j] = (short)f2bf(ws[c8*8+j][d]);
        *(short8*)(o + (size_t)(h*DH + d) * EMB + e0 + c8*8) = v;
    }
}

// ---------- projection GEMM: xp[M,768] = xb[M,768] x wt^T (wt is [n][e]) ----------
// 128x128 tile, BK=64, 4 waves x (64x64), 16x16x32 bf16 MFMA, XOR-swizzled LDS.
__global__ __launch_bounds__(256) void proj_kernel(
    const unsigned short* __restrict__ xb,
    const unsigned short* __restrict__ wt,
    unsigned short* __restrict__ xp)
{
    __shared__ char As[16384];   // [128 rows][8 slots of 16B], slot ^= row&7
    __shared__ char Bs[16384];
    const int t = threadIdx.x;
    const int wv = t >> 6, l = t & 63;
    const int lr = l & 15, lg = l >> 4, l7 = l & 7;
    const int mt = blockIdx.x * 128, nt = blockIdx.y * 128;
    const int mw = (wv >> 1) * 64, nw = (wv & 1) * 64;

    floatx4 acc[4][4];
    #pragma unroll
    for (int a = 0; a < 4; ++a)
        #pragma unroll
        for (int b = 0; b < 4; ++b) acc[a][b] = (floatx4){0.f, 0.f, 0.f, 0.f};

    for (int kt = 0; kt < EMB / 64; ++kt) {
        __syncthreads();
        #pragma unroll
        for (int i = 0; i < 4; ++i) {
            int f = i * 256 + t;          // 1024 tasks: 128 rows x 8 slots
            int row = f >> 3, s = f & 7;
            short8 ga = *(const short8*)(xb + (size_t)(mt + row) * EMB + kt*64 + s*8);
            *(short8*)(As + row*128 + ((s ^ (row & 7)) * 16)) = ga;
            short8 gb = *(const short8*)(wt + (size_t)(nt + row) * EMB + kt*64 + s*8);
            *(short8*)(Bs + row*128 + ((s ^ (row & 7)) * 16)) = gb;
        }
        __syncthreads();
        #pragma unroll
        for (int ks = 0; ks < 2; ++ks) {
            const int sl = (ks*4 + lg) ^ l7;
            short8 af[4], bf[4];
            #pragma unroll
            for (int mf = 0; mf < 4; ++mf)
                af[mf] = *(const short8*)(As + (mw + 16*mf + lr) * 128 + sl*16);
            #pragma unroll
            for (int nf = 0; nf < 4; ++nf)
                bf[nf] = *(const short8*)(Bs + (nw + 16*nf + lr) * 128 + sl*16);
            #pragma unroll
            for (int mf = 0; mf < 4; ++mf)
                #pragma unroll
                for (int nf = 0; nf < 4; ++nf)
                    acc[mf][nf] = __builtin_amdgcn_mfma_f32_16x16x32_bf16(
                        af[mf], bf[nf], acc[mf][nf], 0, 0, 0);
        }
    }
    #pragma unroll
    for (int mf = 0; mf < 4; ++mf)
        #pragma unroll
        for (int r = 0; r < 4; ++r) {
            int m = mt + mw + 16*mf + lg*4 + r;
            unsigned short* op = xp + (size_t)m * EMB + nt + nw + lr;
            #pragma unroll
            for (int nf = 0; nf < 4; ++nf) op[16*nf] = f2bf(acc[mf][nf][r]);
        }
}

// ---------- fused attention: per (qtile, b, h) ----------
// Q in registers; K staged as Ks[kr][d] (mod-12 swizzle) and Kt[d][kr] (XOR-8);
// P via swizzled LDS. Fixed-shift softmax p = exp(s*scale - 12) (exact).
__global__ __launch_bounds__(256) void attn_kernel(
    const unsigned short* __restrict__ kx,   // [16384][768] bf16
    const unsigned short* __restrict__ qx,   // [16384][768] bf16
    float* __restrict__ out)
{
    __shared__ char Ks[64 * 192];    // [64 kr][12 slots], slot' = (s + row) % 12
    __shared__ char Kt[96 * 128];    // [96 d][8 slots],  slot' = s ^ (d&7)
    __shared__ char Ps[128 * 128];   // [128 q][8 slots], slot' = s ^ (q&7)
    const int t = threadIdx.x;
    const int wv = t >> 6, l = t & 63;
    const int lr = l & 15, lg = l >> 4, l7 = l & 7;
    const int q0 = blockIdx.x * 128, b = blockIdx.y, h = blockIdx.z;
    const size_t xcol = (size_t)h * DH;
    const float scale = 0.10206207261596575f;  // 1/sqrt(96)

    // Q fragments in registers: wave owns rows 32*wv .. +32 (mf=0..1), K-dim 96 = 3x32
    short8 qf[2][3];
    #pragma unroll
    for (int mf = 0; mf < 2; ++mf)
        #pragma unroll
        for (int ks = 0; ks < 3; ++ks)
            qf[mf][ks] = *(const short8*)(qx
                + (size_t)(b*SEQ + q0 + 32*wv + 16*mf + lr) * EMB + xcol + ks*32 + lg*8);

    floatx4 oacc[2][6];
    #pragma unroll
    for (int mf = 0; mf < 2; ++mf)
        #pragma unroll
        for (int nf = 0; nf < 6; ++nf) oacc[mf][nf] = (floatx4){0.f, 0.f, 0.f, 0.f};
    float lsum[2][4];
    #pragma unroll
    for (int mf = 0; mf < 2; ++mf)
        #pragma unroll
        for (int r = 0; r < 4; ++r) lsum[mf][r] = 0.f;

    for (int kt = 0; kt < SEQ / 64; ++kt) {
        __syncthreads();
        // stage 64 k-rows: both layouts from the same loads (row pairs for b32 Kt writes)
        #pragma unroll
        for (int i = 0; i < 2; ++i) {
            int f = i * 256 + t;          // 384 tasks: 32 row-pairs x 12 slots
            if (f < 384) {
                int rp = f / 12, s = f - rp * 12;
                int r0 = rp * 2;
                const unsigned short* src = kx + (size_t)(b*SEQ + kt*64 + r0) * EMB + xcol + s*8;
                short8 g0 = *(const short8*)src;
                short8 g1 = *(const short8*)(src + EMB);
                *(short8*)(Ks + r0*192 + ((s + r0) % 12) * 16) = g0;
                *(short8*)(Ks + (r0+1)*192 + ((s + r0 + 1) % 12) * 16) = g1;
                #pragma unroll
                for (int j = 0; j < 8; ++j) {
                    int d = s*8 + j;
                    unsigned int pr = (unsigned int)(unsigned short)g0[j]
                                    | ((unsigned int)(unsigned short)g1[j] << 16);
                    *(unsigned int*)(Kt + d*128 + (((r0 >> 3) ^ (d & 7)) * 16) + (r0 & 7) * 2) = pr;
                }
            }
        }
        __syncthreads();

        // S = Q.K^T  (per wave: 32 q x 64 kr)
        floatx4 sf[2][4];
        #pragma unroll
        for (int mf = 0; mf < 2; ++mf)
            #pragma unroll
            for (int nf = 0; nf < 4; ++nf) sf[mf][nf] = (floatx4){0.f, 0.f, 0.f, 0.f};
        #pragma unroll
        for (int ks = 0; ks < 3; ++ks) {
            short8 bk[4];
            #pragma unroll
            for (int nf = 0; nf < 4; ++nf) {
                int row = 16*nf + lr;
                bk[nf] = *(const short8*)(Ks + row*192 + ((ks*4 + lg + row) % 12) * 16);
            }
            #pragma unroll
            for (int mf = 0; mf < 2; ++mf)
                #pragma unroll
                for (int nf = 0; nf < 4; ++nf)
                    sf[mf][nf] = __builtin_amdgcn_mfma_f32_16x16x32_bf16(
                        qf[mf][ks], bk[nf], sf[mf][nf], 0, 0, 0);
        }

        // p = exp(s*scale - 12); accumulate row-sums; write P (bf16, swizzled)
        #pragma unroll
        for (int mf = 0; mf < 2; ++mf)
            #pragma unroll
            for (int nf = 0; nf < 4; ++nf)
                #pragma unroll
                for (int r = 0; r < 4; ++r) {
                    float p = __expf(fmaf(sf[mf][nf][r], scale, -12.0f));
                    lsum[mf][r] += p;
                    int qrow = 32*wv + 16*mf + lg*4 + r;
                    int kcol = 16*nf + lr;
                    *(unsigned short*)(Ps + qrow*128
                        + (((kcol >> 3) ^ (qrow & 7)) * 16) + (kcol & 7) * 2) = f2bf(p);
                }

        // O += P.Kx   (A = P rows [own 32 q], B = Kt)
        #pragma unroll
        for (int ks2 = 0; ks2 < 2; ++ks2) {
            const int sl = (ks2*4 + lg) ^ l7;
            short8 ap[2];
            #pragma unroll
            for (int mf = 0; mf < 2; ++mf) {
                int row = 32*wv + 16*mf + lr;
                ap[mf] = *(const short8*)(Ps + row*128 + sl*16);
            }
            short8 bv[6];
            #pragma unroll
            for (int nf = 0; nf < 6; ++nf) {
                int d = 16*nf + lr;
                bv[nf] = *(const short8*)(Kt + d*128 + sl*16);
            }
            #pragma unroll
            for (int mf = 0; mf < 2; ++mf)
                #pragma unroll
                for (int nf = 0; nf < 6; ++nf)
                    oacc[mf][nf] = __builtin_amdgcn_mfma_f32_16x16x32_bf16(
                        ap[mf], bv[nf], oacc[mf][nf], 0, 0, 0);
        }
    }

    // full row sums: reduce over the 16 lanes sharing a C-frag row group
    float inv[2][4];
    #pragma unroll
    for (int mf = 0; mf < 2; ++mf)
        #pragma unroll
        for (int r = 0; r < 4; ++r) {
            float v = lsum[mf][r];
            v += __shfl_xor(v, 1);
            v += __shfl_xor(v, 2);
            v += __shfl_xor(v, 4);
            v += __shfl_xor(v, 8);
            inv[mf][r] = 1.0f / v;
        }
    #pragma unroll
    for (int mf = 0; mf < 2; ++mf)
        #pragma unroll
        for (int r = 0; r < 4; ++r) {
            int q = q0 + 32*wv + 16*mf + lg*4 + r;
            float* op = out + (size_t)(b*SEQ + q) * (NHEAD*DH) + xcol + lr;
            #pragma unroll
            for (int nf = 0; nf < 6; ++nf) op[16*nf] = oacc[mf][nf][r] * inv[mf][r];
        }
}

extern "C" void kernel_launch(void* const* d_in, const int* in_sizes, int n_in,
                              void* d_out, int out_size, void* d_ws, size_t ws_size,
                              hipStream_t stream) {
    const float* kin = (const float*)d_in[0];
    const float* qin = (const float*)d_in[1];
    const float* wk  = (const float*)d_in[2];
    const float* wq  = (const float*)d_in[3];
    float* out = (float*)d_out;

    unsigned short* wsu = (unsigned short*)d_ws;
    const size_t SZX = (size_t)MROWS * EMB;          // 12,582,912 elems
    unsigned short* xbk = wsu;                        // bf16 k
    unsigned short* xbq = wsu + SZX;                  // bf16 q
    unsigned short* kxb = wsu + 2*SZX;                // projected K (bf16)
    unsigned short* wtk = wsu + 3*SZX;                // W_k^T [768][768]
    unsigned short* wtq = wtk + (size_t)EMB * (NHEAD*DH);
    unsigned short* qxb = xbk;                        // reuse: xbk dead after proj0

    cvt_x_kernel<<<dim3(MROWS*EMB/8/256, 2), 256, 0, stream>>>(kin, qin, xbk, xbq);
    cvt_w_kernel<<<dim3(NHEAD, EMB/64, 2), 256, 0, stream>>>(wk, wq, wtk, wtq);
    proj_kernel<<<dim3(MROWS/128, NHEAD*DH/128), 256, 0, stream>>>(xbk, wtk, kxb);
    proj_kernel<<<dim3(MROWS/128, NHEAD*DH/128), 256, 0, stream>>>(xbq, wtq, qxb);
    attn_kernel<<<dim3(SEQ/128, NBATCH, NHEAD), 256, 0, stream>>>(kxb, qxb, out);
}